// Round 8
// baseline (504.788 us; speedup 1.0000x reference)
//
#include <hip/hip_runtime.h>
#include <hip/hip_bf16.h>
#include <cstdint>

#define EPS_BN 1e-5f

typedef __attribute__((ext_vector_type(8)))  short bf16x8;   // 8 bf16 = 4 VGPRs
typedef __attribute__((ext_vector_type(16))) float f32x16;   // MFMA 32x32 acc
typedef __attribute__((ext_vector_type(4)))  unsigned short u16x4;

#define MFMA32(a, b, c) __builtin_amdgcn_mfma_f32_32x32x16_bf16(a, b, c, 0, 0, 0)

// async global->LDS, 16B/lane: per-lane GLOBAL src, LDS dst = uniform base + lane*16
#define GLOAD_LDS16(gsrc, ldst) \
    __builtin_amdgcn_global_load_lds((const __attribute__((address_space(1))) void*)(gsrc), \
                                     (__attribute__((address_space(3))) void*)(ldst), 16, 0, 0)

// ---------------------------------------------------------------------------
// build transposed inverted map: invT[k*n_down + s] = g  (s unique per k).
// Table pre-memset to 0xFF (-1 = miss).
// ---------------------------------------------------------------------------
__global__ void build_inv(const int* __restrict__ gather, const int* __restrict__ scatter,
                          long total, int m, int* __restrict__ invT, int n_down) {
    long i = (long)blockIdx.x * blockDim.x + threadIdx.x;
    if (i >= total) return;
    int s = scatter[i];
    if (s < n_down) {
        int k = (int)(i / m);
        invT[(long)k * n_down + s] = gather[i];
    }
}

// feat f32[n_in][32] -> bf16 [n_in+1][32] (pad row zero); also zero ybf pad row.
__global__ void fcvt(const float* __restrict__ f, unsigned short* __restrict__ fb,
                     unsigned short* __restrict__ ybf_pad, long n_in) {
    long t = (long)blockIdx.x * blockDim.x + threadIdx.x;
    long e = t * 4;
    long total = n_in * 32;
    if (e < total) {
        float4 v = *(const float4*)(f + e);
        u16x4 o;
        __hip_bfloat16 h;
        h = __float2bfloat16(v.x); o.x = *(unsigned short*)&h;
        h = __float2bfloat16(v.y); o.y = *(unsigned short*)&h;
        h = __float2bfloat16(v.z); o.z = *(unsigned short*)&h;
        h = __float2bfloat16(v.w); o.w = *(unsigned short*)&h;
        *(u16x4*)(fb + e) = o;
    } else if (e < total + 32) {
        u16x4 z = {0, 0, 0, 0};
        *(u16x4*)(fb + e) = z;
    }
    if (blockIdx.x == 0 && threadIdx.x < 16) {
        u16x4 z = {0, 0, 0, 0};
        ((u16x4*)ybf_pad)[threadIdx.x] = z;
    }
}

// w_ref f32[81][64cin][64cout] -> bf16 wt[k][kq(4)][col(64)][16]: slot
// (col, lhi*8+j) of kq holds w[cin = kq*16+lhi*8+j][col] -> one coalesced b128
// per (kq, ntile) B-fragment load.
__global__ void wcvt_r(const float* __restrict__ w, unsigned short* __restrict__ wt) {
    int e = blockIdx.x * 256 + threadIdx.x;      // 81*4096
    int k = e >> 12, r = e & 4095;
    int cin = ((r >> 10) << 4) + (r & 15);
    int col = (r >> 4) & 63;
    __hip_bfloat16 h = __float2bfloat16(w[(k << 12) + (cin << 6) + col]);
    wt[e] = *(unsigned short*)&h;
}

// w_down f32[16][32cin][64cout] -> bf16 wtd[k][kq(2)][col(64)][16]
__global__ void wcvt_d(const float* __restrict__ w, unsigned short* __restrict__ wt) {
    int e = blockIdx.x * 256 + threadIdx.x;      // 16*2048
    int k = e >> 11, r = e & 2047;
    int cin = ((r >> 10) << 4) + (r & 15);
    int col = (r >> 4) & 63;
    __hip_bfloat16 h = __float2bfloat16(w[(k << 11) + (cin << 6) + col]);
    wt[e] = *(unsigned short*)&h;
}

// ---------------------------------------------------------------------------
// Stage 1: MFMA bf16, K=32, one wave = 32 rows. 91% pad-row gathers (L1-hot).
// ---------------------------------------------------------------------------
__global__ __launch_bounds__(256, 4) void conv_down_mfma(
        const unsigned short* __restrict__ fb, const unsigned short* __restrict__ wtd,
        const int* __restrict__ invd,
        const float* __restrict__ gamma, const float* __restrict__ beta,
        const float* __restrict__ mean, const float* __restrict__ var,
        unsigned short* __restrict__ y, int n_down, int n_in) {
    int  tid  = threadIdx.x;
    int  lane = tid & 63, l31 = lane & 31, lhi = lane >> 5;
    long wv   = ((long)blockIdx.x * 256 + tid) >> 6;
    long o0   = wv * 32;
    if (o0 >= n_down) return;

    int  oA = (int)(o0 + l31 < n_down ? o0 + l31 : n_down - 1);
    const short* ysb = (const short*)fb;

#define LDI_D(k) invd[(size_t)(k) * n_down + oA]
#define GATH_D(dst, g) { \
        const short* p = ysb + (size_t)((g) < 0 ? n_in : (g)) * 32 + lhi * 8; \
        dst[0] = *(const bf16x8*)p; dst[1] = *(const bf16x8*)(p + 16); }

    int g0 = LDI_D(0), gq1 = LDI_D(1), gq2 = LDI_D(2);
    bf16x8 ac[2];
    GATH_D(ac, g0);
    f32x16 acc0 = {}, acc1 = {};
    const short* wp = (const short*)wtd + l31 * 16 + lhi * 8;

    for (int k = 0; k < 16; ++k) {
        int gN = (k < 13) ? LDI_D(k + 3) : -1;
        bf16x8 an[2];
        GATH_D(an, gq1);
        const short* wk = wp + k * 2048;
#pragma unroll
        for (int kq = 0; kq < 2; ++kq) {
            bf16x8 b0 = *(const bf16x8*)(wk + kq * 1024);
            bf16x8 b1 = *(const bf16x8*)(wk + kq * 1024 + 512);
            acc0 = MFMA32(ac[kq], b0, acc0);
            acc1 = MFMA32(ac[kq], b1, acc1);
        }
        ac[0] = an[0]; ac[1] = an[1];
        gq1 = gq2; gq2 = gN;
    }

#pragma unroll
    for (int n = 0; n < 2; ++n) {
        int col = n * 32 + l31;
        float iv = gamma[col] * rsqrtf(var[col] + EPS_BN);
        float bb = beta[col] - mean[col] * iv;
        const f32x16& A = n ? acc1 : acc0;
#pragma unroll
        for (int i = 0; i < 16; ++i) {
            long oo = o0 + (i & 3) + 8 * (i >> 2) + 4 * lhi;
            if (oo < n_down) {
                __hip_bfloat16 h = __float2bfloat16(fmaxf(A[i] * iv + bb, 0.f));
                y[oo * 64 + col] = *(unsigned short*)&h;
            }
        }
    }
#undef LDI_D
#undef GATH_D
}

// ---------------------------------------------------------------------------
// Stage 2: MFMA bf16, wave = 64 rows x 64 cols, 81 offsets.
// L2-byte-minimized: 254 B/row (idx 1 + A 8KB + B 8KB per 64 rows).
// A: FRAGMENT-MAJOR per-wave LDS [chunk(8)][row(64)][16B], 3 buffers (depth-2):
//    stage instr j writes chunk j for all 64 rows (lane w <-> row w) -> only
//    ONE idx load/region, and reads are lane-linear (ZERO bank conflicts).
// B: global->reg, 3 named sets (depth-2). idx: 3-rotating queue (depth-2+).
// Period-3 unroll -> all LDS offsets / reg sets static. Barrier-free; one
// counted vmcnt(34)/region (= drain exactly region k-2's 17 loads).
// Block = 2 waves, LDS 48KB -> 3 blocks/CU.
// ---------------------------------------------------------------------------
__global__ __launch_bounds__(128, 2) void conv_ref_mfma(
        const unsigned short* __restrict__ ybf, const unsigned short* __restrict__ wt,
        const int* __restrict__ invr,
        const float* __restrict__ gamma, const float* __restrict__ beta,
        const float* __restrict__ mean, const float* __restrict__ var,
        float* __restrict__ out, int n_down, int nwg) {
    __shared__ char ldsA[2][3][8192];            // [wave][buf][chunk 8][row 64][16B]

    // bijective XCD swizzle (m204)
    int bid = blockIdx.x;
    int q = nwg >> 3, r = nwg & 7;
    int xcd = bid & 7, pos = bid >> 3;
    int swzb = (xcd < r ? xcd * (q + 1) : r * (q + 1) + (xcd - r) * q) + pos;

    const int tid  = threadIdx.x;
    const int lane = tid & 63, l31 = lane & 31, lhi = lane >> 5;
    const int wid  = tid >> 6;
    const long o0  = ((long)swzb * 2 + wid) * 64;
    if (o0 >= n_down) return;                    // barrier-free: early return safe

    // per-lane idx address: lane w <-> output row o0 + w (clamped tail)
    const int oL = (int)(o0 + lane < n_down ? o0 + lane : n_down - 1);
    const char* ybase = (const char*)ybf;
    char* ldsw = &ldsA[wid][0][0];
    const char* laBase = ldsw + lhi * 1024 + l31 * 16;   // A-read base (static offsets on top)

#define LDI(k) invr[(size_t)(k) * n_down + oL]

#define LDB(Bn0, Bn1, k) { \
        const short* wk_ = wp + (size_t)(k) * 4096; \
        _Pragma("unroll") \
        for (int kq = 0; kq < 4; ++kq) { \
            Bn0[kq] = *(const bf16x8*)(wk_ + kq * 1024); \
            Bn1[kq] = *(const bf16x8*)(wk_ + kq * 1024 + 512); } }

    // stage A: chunk j = bytes [j*16, j*16+16) of each gathered row; lane w -> row w
#define STAGE(BUFOFF, qv) { \
        size_t grow_ = (size_t)((qv) < 0 ? n_down : (qv)); \
        const char* src_ = ybase + grow_ * 128; \
        _Pragma("unroll") \
        for (int j = 0; j < 8; ++j) \
            GLOAD_LDS16(src_ + j * 16, ldsw + (BUFOFF) + j * 1024); }

#define WAITR { asm volatile("s_waitcnt vmcnt(34)" ::: "memory"); \
                __builtin_amdgcn_sched_barrier(0); }

    // A-frag: sub-a (rows 0-31) at chunk(kq*2+lhi)*1024 + l31*16; sub-b +512
#define COMPUTE(BUFOFF, Bn0, Bn1) { \
        __builtin_amdgcn_s_setprio(1); \
        _Pragma("unroll") \
        for (int kq = 0; kq < 4; ++kq) { \
            bf16x8 aA = *(const bf16x8*)(laBase + (BUFOFF) + kq * 2048); \
            bf16x8 aB = *(const bf16x8*)(laBase + (BUFOFF) + kq * 2048 + 512); \
            acc0 = MFMA32(aA, Bn0[kq], acc0); \
            acc1 = MFMA32(aA, Bn1[kq], acc1); \
            acc2 = MFMA32(aB, Bn0[kq], acc2); \
            acc3 = MFMA32(aB, Bn1[kq], acc3); } \
        __builtin_amdgcn_s_setprio(0); }

    f32x16 acc0 = {}, acc1 = {}, acc2 = {}, acc3 = {};
    const short* wp = (const short*)wt + l31 * 16 + lhi * 8;
    bf16x8 B00[4], B01[4], B10[4], B11[4], B20[4], B21[4];

    // prologue: invariant at loop entry = 34 in flight, oldest = [A0(8), B0(8)]
    int i0 = LDI(0);
    int i1 = LDI(1);
    STAGE(0, i0);                                // A[0] -> buf0
    LDB(B00, B01, 0);                            // B[0] -> slot0
    STAGE(8192, i1);                             // A[1] -> buf1
    LDB(B10, B11, 1);                            // B[1] -> slot1
    int q0 = LDI(2);                             // idx[2]
    int q1 = LDI(3);                             // idx[3]
    int q2;

    // main loop: 27 iters x 3 regions; prefetch beyond k=80 reads valid ws
    // memory (invr rows <= 84 < 97; wt+<=84*8KB lands in wtd) and is unused.
    for (int k = 0; k < 81; k += 3) {
        // region k (slot 0): compute buf0/B0, stage A[k+2]->buf2, load B[k+2]->slot2
        LDB(B20, B21, k + 2); q2 = LDI(k + 4); STAGE(16384, q0);
        WAITR; COMPUTE(0, B00, B01);
        // region k+1 (slot 1)
        LDB(B00, B01, k + 3); q0 = LDI(k + 5); STAGE(0, q1);
        WAITR; COMPUTE(8192, B10, B11);
        // region k+2 (slot 2)
        LDB(B10, B11, k + 4); q1 = LDI(k + 6); STAGE(8192, q2);
        WAITR; COMPUTE(16384, B20, B21);
    }

    // epilogue: BN + ReLU, f32 out (sub-a rows o0+.., sub-b rows o0+32+..)
#pragma unroll
    for (int m = 0; m < 2; ++m)
#pragma unroll
        for (int n = 0; n < 2; ++n) {
            int col = n * 32 + l31;
            float iv = gamma[col] * rsqrtf(var[col] + EPS_BN);
            float bb = beta[col] - mean[col] * iv;
            const f32x16& A = m == 0 ? (n == 0 ? acc0 : acc1) : (n == 0 ? acc2 : acc3);
#pragma unroll
            for (int i = 0; i < 16; ++i) {
                long oo = o0 + m * 32 + (i & 3) + 8 * (i >> 2) + 4 * lhi;
                if (oo < n_down)
                    out[oo * 64 + col] = fmaxf(A[i] * iv + bb, 0.f);
            }
        }
#undef LDI
#undef LDB
#undef STAGE
#undef WAITR
#undef COMPUTE
}

extern "C" void kernel_launch(void* const* d_in, const int* in_sizes, int n_args,
                              void* d_out, int out_size, void* d_ws, size_t ws_size,
                              hipStream_t stream) {
    const float* feat    = (const float*)d_in[0];
    const float* w_down  = (const float*)d_in[1];
    const float* gamma_d = (const float*)d_in[2];
    const float* beta_d  = (const float*)d_in[3];
    const float* mean_d  = (const float*)d_in[4];
    const float* var_d   = (const float*)d_in[5];
    const float* w_ref   = (const float*)d_in[6];
    const float* gamma_r = (const float*)d_in[7];
    const float* beta_r  = (const float*)d_in[8];
    const float* mean_r  = (const float*)d_in[9];
    const float* var_r   = (const float*)d_in[10];
    const int*   gather_d  = (const int*)d_in[11];
    const int*   scatter_d = (const int*)d_in[12];
    const int*   gather_r  = (const int*)d_in[13];
    const int*   scatter_r = (const int*)d_in[14];

    int n_in   = in_sizes[0] / 32;
    int md     = in_sizes[11] / 16;
    int mr     = in_sizes[13] / 81;
    int n_down = out_size / 64;

    // ws: ybf[(n_down+1)*64]bf16 | featbf[(n_in+1)*32]bf16 | wt[81*4096]bf16 |
    //     wtd[16*2048]bf16 | invr[81*n_down]i32 | invd[16*n_down]i32 (contig for memset)
    char* ws = (char*)d_ws;
    size_t off = 0;
    auto alloc = [&](size_t bytes) { char* p = ws + off; off = (off + bytes + 255) & ~(size_t)255; return p; };
    unsigned short* ybf    = (unsigned short*)alloc((size_t)(n_down + 1) * 64 * 2);
    unsigned short* featbf = (unsigned short*)alloc((size_t)(n_in + 1) * 32 * 2);
    unsigned short* wt     = (unsigned short*)alloc((size_t)81 * 4096 * 2);
    unsigned short* wtd    = (unsigned short*)alloc((size_t)16 * 2048 * 2);
    int* invr = (int*)(ws + off);
    int* invd = invr + (size_t)81 * n_down;

    hipMemsetAsync(invr, 0xFF, (size_t)97 * n_down * sizeof(int), stream);

    long td = 16L * md;
    build_inv<<<(int)((td + 255) / 256), 256, 0, stream>>>(gather_d, scatter_d, td, md, invd, n_down);
    long tr = 81L * mr;
    build_inv<<<(int)((tr + 255) / 256), 256, 0, stream>>>(gather_r, scatter_r, tr, mr, invr, n_down);

    long ft = ((long)n_in * 32 + 32) / 4;
    fcvt<<<(int)((ft + 255) / 256), 256, 0, stream>>>(feat, featbf, ybf + (size_t)n_down * 64, n_in);
    wcvt_r<<<81 * 4096 / 256, 256, 0, stream>>>(w_ref, wt);
    wcvt_d<<<16 * 2048 / 256, 256, 0, stream>>>(w_down, wtd);

    long wavesD  = ((long)n_down + 31) / 32;
    int  blocksD = (int)((wavesD * 64 + 255) / 256);
    conv_down_mfma<<<blocksD, 256, 0, stream>>>(featbf, wtd, invd,
                                                gamma_d, beta_d, mean_d, var_d,
                                                ybf, n_down, n_in);

    int blocksR = (n_down + 127) / 128;          // 2 waves x 64 rows per block
    conv_ref_mfma<<<blocksR, 128, 0, stream>>>(ybf, wt, invr,
                                               gamma_r, beta_r, mean_r, var_r,
                                               (float*)d_out, n_down, blocksR);
}

// Round 9
// 501.524 us; speedup vs baseline: 1.0065x; 1.0065x over previous
//
#include <hip/hip_runtime.h>
#include <hip/hip_bf16.h>
#include <cstdint>

#define EPS_BN 1e-5f

typedef __attribute__((ext_vector_type(8)))  short bf16x8;   // 8 bf16 = 4 VGPRs
typedef __attribute__((ext_vector_type(16))) float f32x16;   // MFMA 32x32 acc
typedef __attribute__((ext_vector_type(4)))  unsigned short u16x4;

#define MFMA32(a, b, c) __builtin_amdgcn_mfma_f32_32x32x16_bf16(a, b, c, 0, 0, 0)

// async global->LDS, 16B/lane: per-lane GLOBAL src, LDS dst = uniform base + lane*16
#define GLOAD_LDS16(gsrc, ldst) \
    __builtin_amdgcn_global_load_lds((const __attribute__((address_space(1))) void*)(gsrc), \
                                     (__attribute__((address_space(3))) void*)(ldst), 16, 0, 0)

// ---------------------------------------------------------------------------
// build transposed inverted map: invT[k*n_down + s] = g  (s unique per k).
// Table pre-memset to 0xFF (-1 = miss).
// ---------------------------------------------------------------------------
__global__ void build_inv(const int* __restrict__ gather, const int* __restrict__ scatter,
                          long total, int m, int* __restrict__ invT, int n_down) {
    long i = (long)blockIdx.x * blockDim.x + threadIdx.x;
    if (i >= total) return;
    int s = scatter[i];
    if (s < n_down) {
        int k = (int)(i / m);
        invT[(long)k * n_down + s] = gather[i];
    }
}

// feat f32[n_in][32] -> bf16 [n_in+1][32] (pad row zero); also zero ybf pad row.
__global__ void fcvt(const float* __restrict__ f, unsigned short* __restrict__ fb,
                     unsigned short* __restrict__ ybf_pad, long n_in) {
    long t = (long)blockIdx.x * blockDim.x + threadIdx.x;
    long e = t * 4;
    long total = n_in * 32;
    if (e < total) {
        float4 v = *(const float4*)(f + e);
        u16x4 o;
        __hip_bfloat16 h;
        h = __float2bfloat16(v.x); o.x = *(unsigned short*)&h;
        h = __float2bfloat16(v.y); o.y = *(unsigned short*)&h;
        h = __float2bfloat16(v.z); o.z = *(unsigned short*)&h;
        h = __float2bfloat16(v.w); o.w = *(unsigned short*)&h;
        *(u16x4*)(fb + e) = o;
    } else if (e < total + 32) {
        u16x4 z = {0, 0, 0, 0};
        *(u16x4*)(fb + e) = z;
    }
    if (blockIdx.x == 0 && threadIdx.x < 16) {
        u16x4 z = {0, 0, 0, 0};
        ((u16x4*)ybf_pad)[threadIdx.x] = z;
    }
}

// w_ref f32[81][64cin][64cout] -> bf16 wt[k][kq(4)][col(64)][16]: slot
// (col, lhi*8+j) of kq holds w[cin = kq*16+lhi*8+j][col] -> one coalesced b128
// per (kq, ntile) B-fragment load.
__global__ void wcvt_r(const float* __restrict__ w, unsigned short* __restrict__ wt) {
    int e = blockIdx.x * 256 + threadIdx.x;      // 81*4096
    int k = e >> 12, r = e & 4095;
    int cin = ((r >> 10) << 4) + (r & 15);
    int col = (r >> 4) & 63;
    __hip_bfloat16 h = __float2bfloat16(w[(k << 12) + (cin << 6) + col]);
    wt[e] = *(unsigned short*)&h;
}

// w_down f32[16][32cin][64cout] -> bf16 wtd[k][kq(2)][col(64)][16]
__global__ void wcvt_d(const float* __restrict__ w, unsigned short* __restrict__ wt) {
    int e = blockIdx.x * 256 + threadIdx.x;      // 16*2048
    int k = e >> 11, r = e & 2047;
    int cin = ((r >> 10) << 4) + (r & 15);
    int col = (r >> 4) & 63;
    __hip_bfloat16 h = __float2bfloat16(w[(k << 11) + (cin << 6) + col]);
    wt[e] = *(unsigned short*)&h;
}

// ---------------------------------------------------------------------------
// Stage 1: MFMA bf16, K=32, one wave = 32 rows. 91% pad-row gathers (L1-hot).
// ---------------------------------------------------------------------------
__global__ __launch_bounds__(256, 4) void conv_down_mfma(
        const unsigned short* __restrict__ fb, const unsigned short* __restrict__ wtd,
        const int* __restrict__ invd,
        const float* __restrict__ gamma, const float* __restrict__ beta,
        const float* __restrict__ mean, const float* __restrict__ var,
        unsigned short* __restrict__ y, int n_down, int n_in) {
    int  tid  = threadIdx.x;
    int  lane = tid & 63, l31 = lane & 31, lhi = lane >> 5;
    long wv   = ((long)blockIdx.x * 256 + tid) >> 6;
    long o0   = wv * 32;
    if (o0 >= n_down) return;

    int  oA = (int)(o0 + l31 < n_down ? o0 + l31 : n_down - 1);
    const short* ysb = (const short*)fb;

#define LDI_D(k) invd[(size_t)(k) * n_down + oA]
#define GATH_D(dst, g) { \
        const short* p = ysb + (size_t)((g) < 0 ? n_in : (g)) * 32 + lhi * 8; \
        dst[0] = *(const bf16x8*)p; dst[1] = *(const bf16x8*)(p + 16); }

    int g0 = LDI_D(0), gq1 = LDI_D(1), gq2 = LDI_D(2);
    bf16x8 ac[2];
    GATH_D(ac, g0);
    f32x16 acc0 = {}, acc1 = {};
    const short* wp = (const short*)wtd + l31 * 16 + lhi * 8;

    for (int k = 0; k < 16; ++k) {
        int gN = (k < 13) ? LDI_D(k + 3) : -1;
        bf16x8 an[2];
        GATH_D(an, gq1);
        const short* wk = wp + k * 2048;
#pragma unroll
        for (int kq = 0; kq < 2; ++kq) {
            bf16x8 b0 = *(const bf16x8*)(wk + kq * 1024);
            bf16x8 b1 = *(const bf16x8*)(wk + kq * 1024 + 512);
            acc0 = MFMA32(ac[kq], b0, acc0);
            acc1 = MFMA32(ac[kq], b1, acc1);
        }
        ac[0] = an[0]; ac[1] = an[1];
        gq1 = gq2; gq2 = gN;
    }

#pragma unroll
    for (int n = 0; n < 2; ++n) {
        int col = n * 32 + l31;
        float iv = gamma[col] * rsqrtf(var[col] + EPS_BN);
        float bb = beta[col] - mean[col] * iv;
        const f32x16& A = n ? acc1 : acc0;
#pragma unroll
        for (int i = 0; i < 16; ++i) {
            long oo = o0 + (i & 3) + 8 * (i >> 2) + 4 * lhi;
            if (oo < n_down) {
                __hip_bfloat16 h = __float2bfloat16(fmaxf(A[i] * iv + bb, 0.f));
                y[oo * 64 + col] = *(unsigned short*)&h;
            }
        }
    }
#undef LDI_D
#undef GATH_D
}

// ---------------------------------------------------------------------------
// Stage 2: MFMA bf16, wave = 128 rows x 64 cols, 81 offsets (R4 structure at
// M=128: B and idx line-requests amortized 2x -> 3.06 cy/row line-model vs
// R4's 4.06). A: per-wave SINGLE 16KB LDS buffer, 1-region lookahead:
//   vmcnt(2) [A[k],B[k],idx[k+1] drained; idx[k+2] left in flight]
//   -> compute -> lgkmcnt(0) [reads retired] -> stage A[k+1]/B[k+1]/idx[k+3].
// Region wall (~3000cy, 8 waves sharing TA) >> 900cy gather latency -> hidden.
// B: ONE register set (loads issue after consuming MFMAs; WAR-safe by program
// order) keeps unified regs ~224. Grouped-row staging (8 rows/instr = 16
// lines) per the calibrated TA line model. 4-wave block, 64KB LDS, 2 blk/CU.
// ---------------------------------------------------------------------------
__global__ __launch_bounds__(256, 2) void conv_ref_mfma(
        const unsigned short* __restrict__ ybf, const unsigned short* __restrict__ wt,
        const int* __restrict__ invr,
        const float* __restrict__ gamma, const float* __restrict__ beta,
        const float* __restrict__ mean, const float* __restrict__ var,
        float* __restrict__ out, int n_down, int nwg) {
    __shared__ char ldsA[4][16384];              // [wave][128 rows x 128B]

    // bijective XCD swizzle (m204)
    int bid = blockIdx.x;
    int q = nwg >> 3, r = nwg & 7;
    int xcd = bid & 7, pos = bid >> 3;
    int swzb = (xcd < r ? xcd * (q + 1) : r * (q + 1) + (xcd - r) * q) + pos;

    const int tid  = threadIdx.x;
    const int lane = tid & 63, l31 = lane & 31, lhi = lane >> 5;
    const int wid  = tid >> 6;
    const long o0  = ((long)swzb * 4 + wid) * 128;
    if (o0 >= n_down) return;                    // barrier-free: early return safe

    // per-lane idx addresses: lane <-> rows (lane) and (64+lane), clamped tail
    const int oLa = (int)(o0 + lane      < n_down ? o0 + lane      : n_down - 1);
    const int oLb = (int)(o0 + 64 + lane < n_down ? o0 + 64 + lane : n_down - 1);
    const char* ybase = (const char*)ybf;
    char* ldsw = &ldsA[wid][0];
    // stage instr j covers rows j*8+(lane>>3); src slot ((lane&7) ^ (lane>>3))*16
    const int swz = (((lane & 7) ^ (lane >> 3)) << 4);

#define LDI(k, pa, pb) { const int* p_ = invr + (size_t)(k) * n_down; \
                         pa = p_[oLa]; pb = p_[oLb]; }

    int gi[16];                                  // stage-row indices (static idx)
#define BPERM(pa, pb) { \
        _Pragma("unroll") \
        for (int j = 0; j < 8; ++j) gi[j]     = __shfl((pa), j * 8 + (lane >> 3)); \
        _Pragma("unroll") \
        for (int j = 0; j < 8; ++j) gi[8 + j] = __shfl((pb), j * 8 + (lane >> 3)); }

#define STAGE() { \
        _Pragma("unroll") \
        for (int j = 0; j < 16; ++j) { \
            size_t grow_ = (size_t)(gi[j] < 0 ? n_down : gi[j]); \
            GLOAD_LDS16(ybase + grow_ * 128 + swz, ldsw + j * 1024); } }

#define LDB(k) { \
        const short* wk_ = wp + (size_t)(k) * 4096; \
        _Pragma("unroll") \
        for (int kq = 0; kq < 4; ++kq) { \
            B0[kq] = *(const bf16x8*)(wk_ + kq * 1024); \
            B1[kq] = *(const bf16x8*)(wk_ + kq * 1024 + 512); } }

    const int rsw   = (l31 & 7) << 4;
    const int lhi16 = lhi * 16;

#define COMPUTE() { \
        __builtin_amdgcn_s_setprio(1); \
        _Pragma("unroll") \
        for (int kq = 0; kq < 4; ++kq) { \
            int fo = (kq * 32 + lhi16) ^ rsw; \
            _Pragma("unroll") \
            for (int m = 0; m < 4; ++m) { \
                bf16x8 a_ = *(const bf16x8*)(ldsw + (m * 32 + l31) * 128 + fo); \
                acc[m][0] = MFMA32(a_, B0[kq], acc[m][0]); \
                acc[m][1] = MFMA32(a_, B1[kq], acc[m][1]); } } \
        __builtin_amdgcn_s_setprio(0); }

    f32x16 acc[4][2] = {};
    const short* wp = (const short*)wt + l31 * 16 + lhi * 8;
    bf16x8 B0[4], B1[4];
    int pa1, pb1, pa2, pb2, t0a, t0b, ta, tb;

    // prologue: idx[0..2]; A[0] staged; B[0]
    LDI(0, t0a, t0b);
    LDI(1, pa1, pb1);
    LDI(2, pa2, pb2);
    asm volatile("s_waitcnt vmcnt(4)" ::: "memory");     // idx[0] arrived
    __builtin_amdgcn_sched_barrier(0);
    BPERM(t0a, t0b);
    STAGE();                                     // A[0]
    LDB(0);                                      // B[0]
    // in flight entering loop: A[0](16) + B[0](8) + idx[1](2) + idx[2](2) = 28

    // main loop: regions k = 0..79; region 80 in epilogue.
    // invariant at region-k top: in flight = A[k](16)+B[k](8)+idx[k+1](2)+idx[k+2](2)
    for (int k = 0; k < 80; ++k) {
        asm volatile("s_waitcnt vmcnt(2)" ::: "memory"); // A[k],B[k],idx[k+1] done
        __builtin_amdgcn_sched_barrier(0);
        BPERM(pa1, pb1);                         // rows for A[k+1] (hidden under MFMAs)
        COMPUTE();
        asm volatile("s_waitcnt lgkmcnt(0)" ::: "memory"); // LDS reads retired
        __builtin_amdgcn_sched_barrier(0);
        STAGE();                                 // A[k+1]
        LDB(k + 1);                              // B[k+1] (k=79 -> reads wtd region, valid)
        LDI(k + 3, ta, tb);                      // idx[k+3] (<= 82 < 97, valid)
        pa1 = pa2; pb1 = pb2; pa2 = ta; pb2 = tb;
    }
    // region 80
    asm volatile("s_waitcnt vmcnt(2)" ::: "memory");
    __builtin_amdgcn_sched_barrier(0);
    COMPUTE();

    // epilogue: BN + ReLU, f32 out
#pragma unroll
    for (int m = 0; m < 4; ++m)
#pragma unroll
        for (int n = 0; n < 2; ++n) {
            int col = n * 32 + l31;
            float iv = gamma[col] * rsqrtf(var[col] + EPS_BN);
            float bb = beta[col] - mean[col] * iv;
#pragma unroll
            for (int i = 0; i < 16; ++i) {
                long oo = o0 + m * 32 + (i & 3) + 8 * (i >> 2) + 4 * lhi;
                if (oo < n_down)
                    out[oo * 64 + col] = fmaxf(acc[m][n][i] * iv + bb, 0.f);
            }
        }
#undef LDI
#undef BPERM
#undef STAGE
#undef LDB
#undef COMPUTE
}

extern "C" void kernel_launch(void* const* d_in, const int* in_sizes, int n_args,
                              void* d_out, int out_size, void* d_ws, size_t ws_size,
                              hipStream_t stream) {
    const float* feat    = (const float*)d_in[0];
    const float* w_down  = (const float*)d_in[1];
    const float* gamma_d = (const float*)d_in[2];
    const float* beta_d  = (const float*)d_in[3];
    const float* mean_d  = (const float*)d_in[4];
    const float* var_d   = (const float*)d_in[5];
    const float* w_ref   = (const float*)d_in[6];
    const float* gamma_r = (const float*)d_in[7];
    const float* beta_r  = (const float*)d_in[8];
    const float* mean_r  = (const float*)d_in[9];
    const float* var_r   = (const float*)d_in[10];
    const int*   gather_d  = (const int*)d_in[11];
    const int*   scatter_d = (const int*)d_in[12];
    const int*   gather_r  = (const int*)d_in[13];
    const int*   scatter_r = (const int*)d_in[14];

    int n_in   = in_sizes[0] / 32;
    int md     = in_sizes[11] / 16;
    int mr     = in_sizes[13] / 81;
    int n_down = out_size / 64;

    // ws: ybf[(n_down+1)*64]bf16 | featbf[(n_in+1)*32]bf16 | wt[81*4096]bf16 |
    //     wtd[16*2048]bf16 | invr[81*n_down]i32 | invd[16*n_down]i32 (contig for memset)
    char* ws = (char*)d_ws;
    size_t off = 0;
    auto alloc = [&](size_t bytes) { char* p = ws + off; off = (off + bytes + 255) & ~(size_t)255; return p; };
    unsigned short* ybf    = (unsigned short*)alloc((size_t)(n_down + 1) * 64 * 2);
    unsigned short* featbf = (unsigned short*)alloc((size_t)(n_in + 1) * 32 * 2);
    unsigned short* wt     = (unsigned short*)alloc((size_t)81 * 4096 * 2);
    unsigned short* wtd    = (unsigned short*)alloc((size_t)16 * 2048 * 2);
    int* invr = (int*)(ws + off);
    int* invd = invr + (size_t)81 * n_down;

    hipMemsetAsync(invr, 0xFF, (size_t)97 * n_down * sizeof(int), stream);

    long td = 16L * md;
    build_inv<<<(int)((td + 255) / 256), 256, 0, stream>>>(gather_d, scatter_d, td, md, invd, n_down);
    long tr = 81L * mr;
    build_inv<<<(int)((tr + 255) / 256), 256, 0, stream>>>(gather_r, scatter_r, tr, mr, invr, n_down);

    long ft = ((long)n_in * 32 + 32) / 4;
    fcvt<<<(int)((ft + 255) / 256), 256, 0, stream>>>(feat, featbf, ybf + (size_t)n_down * 64, n_in);
    wcvt_r<<<81 * 4096 / 256, 256, 0, stream>>>(w_ref, wt);
    wcvt_d<<<16 * 2048 / 256, 256, 0, stream>>>(w_down, wtd);

    long wavesD  = ((long)n_down + 31) / 32;
    int  blocksD = (int)((wavesD * 64 + 255) / 256);
    conv_down_mfma<<<blocksD, 256, 0, stream>>>(featbf, wtd, invd,
                                                gamma_d, beta_d, mean_d, var_d,
                                                ybf, n_down, n_in);

    int blocksR = (n_down + 511) / 512;          // 4 waves x 128 rows per block
    conv_ref_mfma<<<blocksR, 256, 0, stream>>>(ybf, wt, invr,
                                               gamma_r, beta_r, mean_r, var_r,
                                               (float*)d_out, n_down, blocksR);
}

// Round 10
// 481.454 us; speedup vs baseline: 1.0485x; 1.0417x over previous
//
#include <hip/hip_runtime.h>
#include <hip/hip_bf16.h>
#include <cstdint>

#define EPS_BN 1e-5f

typedef __attribute__((ext_vector_type(8)))  short bf16x8;   // 8 bf16 = 4 VGPRs
typedef __attribute__((ext_vector_type(16))) float f32x16;   // MFMA 32x32 acc
typedef __attribute__((ext_vector_type(4)))  unsigned short u16x4;

#define MFMA32(a, b, c) __builtin_amdgcn_mfma_f32_32x32x16_bf16(a, b, c, 0, 0, 0)

// async global->LDS, 16B/lane: per-lane GLOBAL src, LDS dst = uniform base + lane*16
#define GLOAD_LDS16(gsrc, ldst) \
    __builtin_amdgcn_global_load_lds((const __attribute__((address_space(1))) void*)(gsrc), \
                                     (__attribute__((address_space(3))) void*)(ldst), 16, 0, 0)

// ---------------------------------------------------------------------------
// build transposed inverted map: invT[k*n_down + s] = g  (s unique per k).
// Table pre-memset to 0xFF (-1 = miss).
// ---------------------------------------------------------------------------
__global__ void build_inv(const int* __restrict__ gather, const int* __restrict__ scatter,
                          long total, int m, int* __restrict__ invT, int n_down) {
    long i = (long)blockIdx.x * blockDim.x + threadIdx.x;
    if (i >= total) return;
    int s = scatter[i];
    if (s < n_down) {
        int k = (int)(i / m);
        invT[(long)k * n_down + s] = gather[i];
    }
}

// feat f32[n_in][32] -> bf16 [n_in+1][32] (pad row zero); also zero ybf pad row.
__global__ void fcvt(const float* __restrict__ f, unsigned short* __restrict__ fb,
                     unsigned short* __restrict__ ybf_pad, long n_in) {
    long t = (long)blockIdx.x * blockDim.x + threadIdx.x;
    long e = t * 4;
    long total = n_in * 32;
    if (e < total) {
        float4 v = *(const float4*)(f + e);
        u16x4 o;
        __hip_bfloat16 h;
        h = __float2bfloat16(v.x); o.x = *(unsigned short*)&h;
        h = __float2bfloat16(v.y); o.y = *(unsigned short*)&h;
        h = __float2bfloat16(v.z); o.z = *(unsigned short*)&h;
        h = __float2bfloat16(v.w); o.w = *(unsigned short*)&h;
        *(u16x4*)(fb + e) = o;
    } else if (e < total + 32) {
        u16x4 z = {0, 0, 0, 0};
        *(u16x4*)(fb + e) = z;
    }
    if (blockIdx.x == 0 && threadIdx.x < 16) {
        u16x4 z = {0, 0, 0, 0};
        ((u16x4*)ybf_pad)[threadIdx.x] = z;
    }
}

// w_ref f32[81][64cin][64cout] -> bf16 wt[k][kq(4)][col(64)][16]: slot
// (col, lhi*8+j) of kq holds w[cin = kq*16+lhi*8+j][col] -> one coalesced b128
// per (kq, ntile) B-fragment load.
__global__ void wcvt_r(const float* __restrict__ w, unsigned short* __restrict__ wt) {
    int e = blockIdx.x * 256 + threadIdx.x;      // 81*4096
    int k = e >> 12, r = e & 4095;
    int cin = ((r >> 10) << 4) + (r & 15);
    int col = (r >> 4) & 63;
    __hip_bfloat16 h = __float2bfloat16(w[(k << 12) + (cin << 6) + col]);
    wt[e] = *(unsigned short*)&h;
}

// w_down f32[16][32cin][64cout] -> bf16 wtd[k][kq(2)][col(64)][16]
__global__ void wcvt_d(const float* __restrict__ w, unsigned short* __restrict__ wt) {
    int e = blockIdx.x * 256 + threadIdx.x;      // 16*2048
    int k = e >> 11, r = e & 2047;
    int cin = ((r >> 10) << 4) + (r & 15);
    int col = (r >> 4) & 63;
    __hip_bfloat16 h = __float2bfloat16(w[(k << 11) + (cin << 6) + col]);
    wt[e] = *(unsigned short*)&h;
}

// ---------------------------------------------------------------------------
// Stage 1: MFMA bf16, K=32, one wave = 32 rows. 91% pad-row gathers (L1-hot).
// ---------------------------------------------------------------------------
__global__ __launch_bounds__(256, 4) void conv_down_mfma(
        const unsigned short* __restrict__ fb, const unsigned short* __restrict__ wtd,
        const int* __restrict__ invd,
        const float* __restrict__ gamma, const float* __restrict__ beta,
        const float* __restrict__ mean, const float* __restrict__ var,
        unsigned short* __restrict__ y, int n_down, int n_in) {
    int  tid  = threadIdx.x;
    int  lane = tid & 63, l31 = lane & 31, lhi = lane >> 5;
    long wv   = ((long)blockIdx.x * 256 + tid) >> 6;
    long o0   = wv * 32;
    if (o0 >= n_down) return;

    int  oA = (int)(o0 + l31 < n_down ? o0 + l31 : n_down - 1);
    const short* ysb = (const short*)fb;

#define LDI_D(k) invd[(size_t)(k) * n_down + oA]
#define GATH_D(dst, g) { \
        const short* p = ysb + (size_t)((g) < 0 ? n_in : (g)) * 32 + lhi * 8; \
        dst[0] = *(const bf16x8*)p; dst[1] = *(const bf16x8*)(p + 16); }

    int g0 = LDI_D(0), gq1 = LDI_D(1), gq2 = LDI_D(2);
    bf16x8 ac[2];
    GATH_D(ac, g0);
    f32x16 acc0 = {}, acc1 = {};
    const short* wp = (const short*)wtd + l31 * 16 + lhi * 8;

    for (int k = 0; k < 16; ++k) {
        int gN = (k < 13) ? LDI_D(k + 3) : -1;
        bf16x8 an[2];
        GATH_D(an, gq1);
        const short* wk = wp + k * 2048;
#pragma unroll
        for (int kq = 0; kq < 2; ++kq) {
            bf16x8 b0 = *(const bf16x8*)(wk + kq * 1024);
            bf16x8 b1 = *(const bf16x8*)(wk + kq * 1024 + 512);
            acc0 = MFMA32(ac[kq], b0, acc0);
            acc1 = MFMA32(ac[kq], b1, acc1);
        }
        ac[0] = an[0]; ac[1] = an[1];
        gq1 = gq2; gq2 = gN;
    }

#pragma unroll
    for (int n = 0; n < 2; ++n) {
        int col = n * 32 + l31;
        float iv = gamma[col] * rsqrtf(var[col] + EPS_BN);
        float bb = beta[col] - mean[col] * iv;
        const f32x16& A = n ? acc1 : acc0;
#pragma unroll
        for (int i = 0; i < 16; ++i) {
            long oo = o0 + (i & 3) + 8 * (i >> 2) + 4 * lhi;
            if (oo < n_down) {
                __hip_bfloat16 h = __float2bfloat16(fmaxf(A[i] * iv + bb, 0.f));
                y[oo * 64 + col] = *(unsigned short*)&h;
            }
        }
    }
#undef LDI_D
#undef GATH_D
}

// ---------------------------------------------------------------------------
// Stage 2: MFMA bf16, wave = 128 rows x 64 cols, 81 offsets.
// R9 wave-structure at the R4-proven occupancy point: 2-WAVE blocks (128 thr)
// -> ~2060 blocks, 32KB LDS/block, ~252 unified regs -> 4 blocks/CU =
// 8 waves/CU. Line model: (A 256 + B 128 + idx 8) lines per 128 rows =
// 3.06 cy/row at the calibrated ~0.5 lines/cy TA rate (R4 = 4.06).
// A: per-wave SINGLE 16KB LDS buffer; 1-region lookahead; barrier-free.
// Steady-state vmcnt queue at region-k top: [idx(k+1), A(k)x16, B(k)x8,
// idx(k+2)] -> vmcnt(2) drains A/B/idx(k+1), leaves idx(k+2).
// ---------------------------------------------------------------------------
__global__ __launch_bounds__(128, 2) void conv_ref_mfma(
        const unsigned short* __restrict__ ybf, const unsigned short* __restrict__ wt,
        const int* __restrict__ invr,
        const float* __restrict__ gamma, const float* __restrict__ beta,
        const float* __restrict__ mean, const float* __restrict__ var,
        float* __restrict__ out, int n_down, int nwg) {
    __shared__ char ldsA[2][16384];              // [wave][128 rows x 128B]

    // bijective XCD swizzle (m204)
    int bid = blockIdx.x;
    int q = nwg >> 3, r = nwg & 7;
    int xcd = bid & 7, pos = bid >> 3;
    int swzb = (xcd < r ? xcd * (q + 1) : r * (q + 1) + (xcd - r) * q) + pos;

    const int tid  = threadIdx.x;
    const int lane = tid & 63, l31 = lane & 31, lhi = lane >> 5;
    const int wid  = tid >> 6;
    const long o0  = ((long)swzb * 2 + wid) * 128;
    if (o0 >= n_down) return;                    // barrier-free: early return safe

    // per-lane idx addresses: lane <-> rows (lane) and (64+lane), clamped tail
    const int oLa = (int)(o0 + lane      < n_down ? o0 + lane      : n_down - 1);
    const int oLb = (int)(o0 + 64 + lane < n_down ? o0 + 64 + lane : n_down - 1);
    const char* ybase = (const char*)ybf;
    char* ldsw = &ldsA[wid][0];
    // stage instr j covers rows j*8+(lane>>3); src slot ((lane&7) ^ (lane>>3))*16
    const int swz = (((lane & 7) ^ (lane >> 3)) << 4);

#define LDI(k, pa, pb) { const int* p_ = invr + (size_t)(k) * n_down; \
                         pa = p_[oLa]; pb = p_[oLb]; }

    int gi[16];                                  // stage-row indices (static idx)
#define BPERM(pa, pb) { \
        _Pragma("unroll") \
        for (int j = 0; j < 8; ++j) gi[j]     = __shfl((pa), j * 8 + (lane >> 3)); \
        _Pragma("unroll") \
        for (int j = 0; j < 8; ++j) gi[8 + j] = __shfl((pb), j * 8 + (lane >> 3)); }

#define STAGE() { \
        _Pragma("unroll") \
        for (int j = 0; j < 16; ++j) { \
            size_t grow_ = (size_t)(gi[j] < 0 ? n_down : gi[j]); \
            GLOAD_LDS16(ybase + grow_ * 128 + swz, ldsw + j * 1024); } }

#define LDB(k) { \
        const short* wk_ = wp + (size_t)(k) * 4096; \
        _Pragma("unroll") \
        for (int kq = 0; kq < 4; ++kq) { \
            B0[kq] = *(const bf16x8*)(wk_ + kq * 1024); \
            B1[kq] = *(const bf16x8*)(wk_ + kq * 1024 + 512); } }

    const int rsw   = (l31 & 7) << 4;
    const int lhi16 = lhi * 16;

#define COMPUTE() { \
        __builtin_amdgcn_s_setprio(1); \
        _Pragma("unroll") \
        for (int kq = 0; kq < 4; ++kq) { \
            int fo = (kq * 32 + lhi16) ^ rsw; \
            _Pragma("unroll") \
            for (int m = 0; m < 4; ++m) { \
                bf16x8 a_ = *(const bf16x8*)(ldsw + (m * 32 + l31) * 128 + fo); \
                acc[m][0] = MFMA32(a_, B0[kq], acc[m][0]); \
                acc[m][1] = MFMA32(a_, B1[kq], acc[m][1]); } } \
        __builtin_amdgcn_s_setprio(0); }

    f32x16 acc[4][2] = {};
    const short* wp = (const short*)wt + l31 * 16 + lhi * 8;
    bf16x8 B0[4], B1[4];
    int pa1, pb1, pa2, pb2, t0a, t0b, ta, tb;

    // prologue -- establishes the steady-state queue invariant:
    LDI(0, t0a, t0b);                            // idx[0] (2)
    LDI(1, pa1, pb1);                            // idx[1] (2)
    asm volatile("s_waitcnt vmcnt(2)" ::: "memory");   // idx[0] done, idx[1] in flight
    __builtin_amdgcn_sched_barrier(0);
    BPERM(t0a, t0b);
    STAGE();                                     // A[0] (16)
    LDB(0);                                      // B[0] (8)
    LDI(2, pa2, pb2);                            // idx[2] (2)
    // queue now (old->new): idx[1](2), A[0](16), B[0](8), idx[2](2) = steady state

    // main loop: regions k = 0..79; region 80 in epilogue.
    for (int k = 0; k < 80; ++k) {
        asm volatile("s_waitcnt vmcnt(2)" ::: "memory"); // A[k],B[k],idx[k+1] done
        __builtin_amdgcn_sched_barrier(0);
        BPERM(pa1, pb1);                         // rows for A[k+1] (hidden under MFMAs)
        COMPUTE();
        asm volatile("s_waitcnt lgkmcnt(0)" ::: "memory"); // LDS reads retired
        __builtin_amdgcn_sched_barrier(0);
        STAGE();                                 // A[k+1] (k=79: harmless valid prefetch)
        LDB(k + 1);                              // B[k+1]
        LDI(k + 3, ta, tb);                      // idx[k+3] (row <= 82 < 97, valid)
        pa1 = pa2; pb1 = pb2; pa2 = ta; pb2 = tb;
    }
    // region 80
    asm volatile("s_waitcnt vmcnt(2)" ::: "memory");
    __builtin_amdgcn_sched_barrier(0);
    COMPUTE();

    // epilogue: BN + ReLU, f32 out
#pragma unroll
    for (int m = 0; m < 4; ++m)
#pragma unroll
        for (int n = 0; n < 2; ++n) {
            int col = n * 32 + l31;
            float iv = gamma[col] * rsqrtf(var[col] + EPS_BN);
            float bb = beta[col] - mean[col] * iv;
#pragma unroll
            for (int i = 0; i < 16; ++i) {
                long oo = o0 + m * 32 + (i & 3) + 8 * (i >> 2) + 4 * lhi;
                if (oo < n_down)
                    out[oo * 64 + col] = fmaxf(acc[m][n][i] * iv + bb, 0.f);
            }
        }
#undef LDI
#undef BPERM
#undef STAGE
#undef LDB
#undef COMPUTE
}

extern "C" void kernel_launch(void* const* d_in, const int* in_sizes, int n_args,
                              void* d_out, int out_size, void* d_ws, size_t ws_size,
                              hipStream_t stream) {
    const float* feat    = (const float*)d_in[0];
    const float* w_down  = (const float*)d_in[1];
    const float* gamma_d = (const float*)d_in[2];
    const float* beta_d  = (const float*)d_in[3];
    const float* mean_d  = (const float*)d_in[4];
    const float* var_d   = (const float*)d_in[5];
    const float* w_ref   = (const float*)d_in[6];
    const float* gamma_r = (const float*)d_in[7];
    const float* beta_r  = (const float*)d_in[8];
    const float* mean_r  = (const float*)d_in[9];
    const float* var_r   = (const float*)d_in[10];
    const int*   gather_d  = (const int*)d_in[11];
    const int*   scatter_d = (const int*)d_in[12];
    const int*   gather_r  = (const int*)d_in[13];
    const int*   scatter_r = (const int*)d_in[14];

    int n_in   = in_sizes[0] / 32;
    int md     = in_sizes[11] / 16;
    int mr     = in_sizes[13] / 81;
    int n_down = out_size / 64;

    // ws: ybf[(n_down+1)*64]bf16 | featbf[(n_in+1)*32]bf16 | wt[81*4096]bf16 |
    //     wtd[16*2048]bf16 | invr[81*n_down]i32 | invd[16*n_down]i32 (contig for memset)
    char* ws = (char*)d_ws;
    size_t off = 0;
    auto alloc = [&](size_t bytes) { char* p = ws + off; off = (off + bytes + 255) & ~(size_t)255; return p; };
    unsigned short* ybf    = (unsigned short*)alloc((size_t)(n_down + 1) * 64 * 2);
    unsigned short* featbf = (unsigned short*)alloc((size_t)(n_in + 1) * 32 * 2);
    unsigned short* wt     = (unsigned short*)alloc((size_t)81 * 4096 * 2);
    unsigned short* wtd    = (unsigned short*)alloc((size_t)16 * 2048 * 2);
    int* invr = (int*)(ws + off);
    int* invd = invr + (size_t)81 * n_down;

    hipMemsetAsync(invr, 0xFF, (size_t)97 * n_down * sizeof(int), stream);

    long td = 16L * md;
    build_inv<<<(int)((td + 255) / 256), 256, 0, stream>>>(gather_d, scatter_d, td, md, invd, n_down);
    long tr = 81L * mr;
    build_inv<<<(int)((tr + 255) / 256), 256, 0, stream>>>(gather_r, scatter_r, tr, mr, invr, n_down);

    long ft = ((long)n_in * 32 + 32) / 4;
    fcvt<<<(int)((ft + 255) / 256), 256, 0, stream>>>(feat, featbf, ybf + (size_t)n_down * 64, n_in);
    wcvt_r<<<81 * 4096 / 256, 256, 0, stream>>>(w_ref, wt);
    wcvt_d<<<16 * 2048 / 256, 256, 0, stream>>>(w_down, wtd);

    long wavesD  = ((long)n_down + 31) / 32;
    int  blocksD = (int)((wavesD * 64 + 255) / 256);
    conv_down_mfma<<<blocksD, 256, 0, stream>>>(featbf, wtd, invd,
                                                gamma_d, beta_d, mean_d, var_d,
                                                ybf, n_down, n_in);

    int blocksR = (n_down + 255) / 256;          // 2 waves x 128 rows per block
    conv_ref_mfma<<<blocksR, 128, 0, stream>>>(ybf, wt, invr,
                                               gamma_r, beta_r, mean_r, var_r,
                                               (float*)d_out, n_down, blocksR);
}

// Round 11
// 403.936 us; speedup vs baseline: 1.2497x; 1.1919x over previous
//
#include <hip/hip_runtime.h>
#include <hip/hip_bf16.h>
#include <cstdint>

#define EPS_BN 1e-5f

typedef __attribute__((ext_vector_type(8)))  short bf16x8;   // 8 bf16 = 4 VGPRs
typedef __attribute__((ext_vector_type(16))) float f32x16;   // MFMA 32x32 acc
typedef __attribute__((ext_vector_type(4)))  unsigned short u16x4;

#define MFMA32(a, b, c) __builtin_amdgcn_mfma_f32_32x32x16_bf16(a, b, c, 0, 0, 0)

// async global->LDS, 16B/lane: per-lane GLOBAL src, LDS dst = uniform base + lane*16
#define GLOAD_LDS16(gsrc, ldst) \
    __builtin_amdgcn_global_load_lds((const __attribute__((address_space(1))) void*)(gsrc), \
                                     (__attribute__((address_space(3))) void*)(ldst), 16, 0, 0)

// ---------------------------------------------------------------------------
// invd (stage-1): plain transposed inverted map invT[k*n_down + s] = g.
// ---------------------------------------------------------------------------
__global__ void build_inv(const int* __restrict__ gather, const int* __restrict__ scatter,
                          long total, int m, int* __restrict__ invT, int n_down) {
    long i = (long)blockIdx.x * blockDim.x + threadIdx.x;
    if (i >= total) return;
    int s = scatter[i];
    if (s < n_down) {
        int k = (int)(i / m);
        invT[(long)k * n_down + s] = gather[i];
    }
}

// ---------------------------------------------------------------------------
// invP (stage-2): PERMUTED inverted map. Within each 64-row block, row r is
// stored at pos(r) = (r>=32?32:0) + (r&7)*4 + ((r>>3)&3), so a wave reads its
// 64 stage indices with TWO coalesced dwordx4 loads already in
// stage-instruction layout (lane ro=lane>>3 gets Q_i = idx[row 8i+ro]) -- no
// cross-lane shuffle (removes 8 ds_bpermute/region from the LDS pipe).
// ---------------------------------------------------------------------------
__global__ void build_invP(const int* __restrict__ gather, const int* __restrict__ scatter,
                           long total, int m, int* __restrict__ invP, int n_down, int nb64) {
    long i = (long)blockIdx.x * blockDim.x + threadIdx.x;
    if (i >= total) return;
    int s = scatter[i];
    if (s < n_down) {
        int k = (int)(i / m);
        int r = s & 63;
        int pos = ((r >> 5) << 5) + ((r & 7) << 2) + ((r >> 3) & 3);
        invP[(size_t)k * nb64 + ((size_t)(s >> 6) << 6) + pos] = gather[i];
    }
}

// feat f32[n_in][32] -> bf16 [n_in+1][32] (pad row zero); also zero ybf pad row.
__global__ void fcvt(const float* __restrict__ f, unsigned short* __restrict__ fb,
                     unsigned short* __restrict__ ybf_pad, long n_in) {
    long t = (long)blockIdx.x * blockDim.x + threadIdx.x;
    long e = t * 4;
    long total = n_in * 32;
    if (e < total) {
        float4 v = *(const float4*)(f + e);
        u16x4 o;
        __hip_bfloat16 h;
        h = __float2bfloat16(v.x); o.x = *(unsigned short*)&h;
        h = __float2bfloat16(v.y); o.y = *(unsigned short*)&h;
        h = __float2bfloat16(v.z); o.z = *(unsigned short*)&h;
        h = __float2bfloat16(v.w); o.w = *(unsigned short*)&h;
        *(u16x4*)(fb + e) = o;
    } else if (e < total + 32) {
        u16x4 z = {0, 0, 0, 0};
        *(u16x4*)(fb + e) = z;
    }
    if (blockIdx.x == 0 && threadIdx.x < 16) {
        u16x4 z = {0, 0, 0, 0};
        ((u16x4*)ybf_pad)[threadIdx.x] = z;
    }
}

// w_ref f32[81][64cin][64cout] -> bf16 wt[k][kq(4)][col(64)][16]: slot
// (col, lhi*8+j) of kq holds w[cin = kq*16+lhi*8+j][col].
__global__ void wcvt_r(const float* __restrict__ w, unsigned short* __restrict__ wt) {
    int e = blockIdx.x * 256 + threadIdx.x;      // 81*4096
    int k = e >> 12, r = e & 4095;
    int cin = ((r >> 10) << 4) + (r & 15);
    int col = (r >> 4) & 63;
    __hip_bfloat16 h = __float2bfloat16(w[(k << 12) + (cin << 6) + col]);
    wt[e] = *(unsigned short*)&h;
}

// w_down f32[16][32cin][64cout] -> bf16 wtd[k][kq(2)][col(64)][16]
__global__ void wcvt_d(const float* __restrict__ w, unsigned short* __restrict__ wt) {
    int e = blockIdx.x * 256 + threadIdx.x;      // 16*2048
    int k = e >> 11, r = e & 2047;
    int cin = ((r >> 10) << 4) + (r & 15);
    int col = (r >> 4) & 63;
    __hip_bfloat16 h = __float2bfloat16(w[(k << 11) + (cin << 6) + col]);
    wt[e] = *(unsigned short*)&h;
}

// ---------------------------------------------------------------------------
// Stage 1: MFMA bf16, K=32, one wave = 32 rows. 91% pad-row gathers (L1-hot).
// ---------------------------------------------------------------------------
__global__ __launch_bounds__(256, 4) void conv_down_mfma(
        const unsigned short* __restrict__ fb, const unsigned short* __restrict__ wtd,
        const int* __restrict__ invd,
        const float* __restrict__ gamma, const float* __restrict__ beta,
        const float* __restrict__ mean, const float* __restrict__ var,
        unsigned short* __restrict__ y, int n_down, int n_in) {
    int  tid  = threadIdx.x;
    int  lane = tid & 63, l31 = lane & 31, lhi = lane >> 5;
    long wv   = ((long)blockIdx.x * 256 + tid) >> 6;
    long o0   = wv * 32;
    if (o0 >= n_down) return;

    int  oA = (int)(o0 + l31 < n_down ? o0 + l31 : n_down - 1);
    const short* ysb = (const short*)fb;

#define LDI_D(k) invd[(size_t)(k) * n_down + oA]
#define GATH_D(dst, g) { \
        const short* p = ysb + (size_t)((g) < 0 ? n_in : (g)) * 32 + lhi * 8; \
        dst[0] = *(const bf16x8*)p; dst[1] = *(const bf16x8*)(p + 16); }

    int g0 = LDI_D(0), gq1 = LDI_D(1), gq2 = LDI_D(2);
    bf16x8 ac[2];
    GATH_D(ac, g0);
    f32x16 acc0 = {}, acc1 = {};
    const short* wp = (const short*)wtd + l31 * 16 + lhi * 8;

    for (int k = 0; k < 16; ++k) {
        int gN = (k < 13) ? LDI_D(k + 3) : -1;
        bf16x8 an[2];
        GATH_D(an, gq1);
        const short* wk = wp + k * 2048;
#pragma unroll
        for (int kq = 0; kq < 2; ++kq) {
            bf16x8 b0 = *(const bf16x8*)(wk + kq * 1024);
            bf16x8 b1 = *(const bf16x8*)(wk + kq * 1024 + 512);
            acc0 = MFMA32(ac[kq], b0, acc0);
            acc1 = MFMA32(ac[kq], b1, acc1);
        }
        ac[0] = an[0]; ac[1] = an[1];
        gq1 = gq2; gq2 = gN;
    }

#pragma unroll
    for (int n = 0; n < 2; ++n) {
        int col = n * 32 + l31;
        float iv = gamma[col] * rsqrtf(var[col] + EPS_BN);
        float bb = beta[col] - mean[col] * iv;
        const f32x16& A = n ? acc1 : acc0;
#pragma unroll
        for (int i = 0; i < 16; ++i) {
            long oo = o0 + (i & 3) + 8 * (i >> 2) + 4 * lhi;
            if (oo < n_down) {
                __hip_bfloat16 h = __float2bfloat16(fmaxf(A[i] * iv + bb, 0.f));
                y[oo * 64 + col] = *(unsigned short*)&h;
            }
        }
    }
#undef LDI_D
#undef GATH_D
}

// ---------------------------------------------------------------------------
// Stage 2: R4 structure (best measured: 277us) minus the idx shuffle.
// Wave = 64 rows x 64 cols, 81 regions. A: per-wave double-buffered LDS via
// global_load_lds (pre-swizzled src); B: global->reg, 2 named sets; idx: two
// dwordx4 loads/region from the PERMUTED table (3 rotating int4 sets, 3-region
// lead, period-6 unroll). Barrier-free. Steady queue at vmcnt point:
// [I(2), A[k](8), B[k](8), I(2), A[k+1](8), B[k+1](8), I(2)] = 38 ->
// vmcnt(20) drains I + A[k] + B[k] exactly. LDS 64KB/block -> 2 blocks/CU.
// ---------------------------------------------------------------------------
__global__ __launch_bounds__(256, 2) void conv_ref_mfma(
        const unsigned short* __restrict__ ybf, const unsigned short* __restrict__ wt,
        const int* __restrict__ invP,
        const float* __restrict__ gamma, const float* __restrict__ beta,
        const float* __restrict__ mean, const float* __restrict__ var,
        float* __restrict__ out, int n_down, int nb64, int nwg) {
    __shared__ char ldsA[4][2][8192];            // [wave][buf][64 rows x 128B]

    // bijective XCD swizzle (m204)
    int bid = blockIdx.x;
    int q = nwg >> 3, r = nwg & 7;
    int xcd = bid & 7, pos = bid >> 3;
    int swzb = (xcd < r ? xcd * (q + 1) : r * (q + 1) + (xcd - r) * q) + pos;

    const int tid  = threadIdx.x;
    const int lane = tid & 63, l31 = lane & 31, lhi = lane >> 5;
    const int wid  = tid >> 6;
    const long o0  = ((long)swzb * 4 + wid) * 64;
    if (o0 >= n_down) return;                    // barrier-free: early return safe

    const int  ro    = lane >> 3;                // 0..7
    const char* ybase = (const char*)ybf;
    char* ldsw = &ldsA[wid][0][0];
    const int swz = (((lane & 7) ^ ro) << 4);    // staged-source slot swizzle

    // idx base for this wave's 64-row block (o0 is a multiple of 64)
    const char* ibase = (const char*)invP + (size_t)o0 * 4 + (size_t)ro * 16;

    // two dwordx4 loads deliver Q0..3 / Q4..7 = idx of rows 8i+ro, i=0..7
#define IDXP(k, S) { const char* p_ = ibase + (size_t)(k) * ((size_t)nb64 * 4); \
        S##a = *(const int4*)p_; S##b = *(const int4*)(p_ + 128); }

#define GL1(qv, BUF, i) { size_t g_ = (size_t)((qv) < 0 ? n_down : (qv)); \
        GLOAD_LDS16(ybase + g_ * 128 + swz, ldsw + (BUF) * 8192 + (i) * 1024); }

#define STAGE(BUF, S) { \
        GL1(S##a.x, BUF, 0); GL1(S##a.y, BUF, 1); GL1(S##a.z, BUF, 2); GL1(S##a.w, BUF, 3); \
        GL1(S##b.x, BUF, 4); GL1(S##b.y, BUF, 5); GL1(S##b.z, BUF, 6); GL1(S##b.w, BUF, 7); }

#define LDB(B0, B1, k) { \
        const short* wk_ = wp + (size_t)(k) * 4096; \
        _Pragma("unroll") \
        for (int kq = 0; kq < 4; ++kq) { \
            B0[kq] = *(const bf16x8*)(wk_ + kq * 1024); \
            B1[kq] = *(const bf16x8*)(wk_ + kq * 1024 + 512); } }

    const int rsw   = (l31 & 7) << 4;
    const int rowA  = l31 * 128, rowB = (32 + l31) * 128;
    const int lhi16 = lhi * 16;

#define COMPUTE(BUF, B0, B1) { \
        const char* la = ldsw + (BUF) * 8192; \
        __builtin_amdgcn_s_setprio(1); \
        _Pragma("unroll") \
        for (int kq = 0; kq < 4; ++kq) { \
            int fo = (kq * 32 + lhi16) ^ rsw; \
            bf16x8 aA = *(const bf16x8*)(la + rowA + fo); \
            bf16x8 aB = *(const bf16x8*)(la + rowB + fo); \
            acc0 = MFMA32(aA, B0[kq], acc0); \
            acc1 = MFMA32(aA, B1[kq], acc1); \
            acc2 = MFMA32(aB, B0[kq], acc2); \
            acc3 = MFMA32(aB, B1[kq], acc3); } \
        __builtin_amdgcn_s_setprio(0); }

    // region kk: stage A[kk+1] into NXT using set S, reload S with idx[kk+4],
    // load B[kk+1], counted wait, compute CUR.
#define REGION(CUR, NXT, S, kk, BC0, BC1, BN0, BN1) { \
        STAGE(NXT, S); \
        LDB(BN0, BN1, (kk) + 1); \
        IDXP((kk) + 4, S); \
        asm volatile("s_waitcnt vmcnt(20)" ::: "memory"); \
        __builtin_amdgcn_sched_barrier(0); \
        COMPUTE(CUR, BC0, BC1); }

    f32x16 acc0 = {}, acc1 = {}, acc2 = {}, acc3 = {};
    const short* wp = (const short*)wt + l31 * 16 + lhi * 8;
    bf16x8 B00[4], B01[4], B10[4], B11[4];
    int4 Ta, Tb, S0a, S0b, S1a, S1b, S2a, S2b;

    // prologue: idx[0..3]; A[0] -> buf0; B[0] -> set0
    IDXP(0, T);
    IDXP(1, S0);
    IDXP(2, S1);
    IDXP(3, S2);
    asm volatile("s_waitcnt vmcnt(6)" ::: "memory");   // T ready
    __builtin_amdgcn_sched_barrier(0);
    STAGE(0, T);
    LDB(B00, B01, 0);

    // 80 staged regions: 13 x 6 (0..77) + 78, 79; region 80 = compute-only.
    for (int k = 0; k < 78; k += 6) {
        REGION(0, 1, S0, k + 0, B00, B01, B10, B11);
        REGION(1, 0, S1, k + 1, B10, B11, B00, B01);
        REGION(0, 1, S2, k + 2, B00, B01, B10, B11);
        REGION(1, 0, S0, k + 3, B10, B11, B00, B01);
        REGION(0, 1, S1, k + 4, B00, B01, B10, B11);
        REGION(1, 0, S2, k + 5, B10, B11, B00, B01);
    }
    REGION(0, 1, S0, 78, B00, B01, B10, B11);
    REGION(1, 0, S1, 79, B10, B11, B00, B01);
    // region 80 (buf0, B set 0); queue = [I(2), A80(8), B80(8), I(2)]
    asm volatile("s_waitcnt vmcnt(2)" ::: "memory");
    __builtin_amdgcn_sched_barrier(0);
    COMPUTE(0, B00, B01);

    // epilogue: BN + ReLU, f32 out
#pragma unroll
    for (int m = 0; m < 2; ++m)
#pragma unroll
        for (int n = 0; n < 2; ++n) {
            int col = n * 32 + l31;
            float iv = gamma[col] * rsqrtf(var[col] + EPS_BN);
            float bb = beta[col] - mean[col] * iv;
            const f32x16& A = m == 0 ? (n == 0 ? acc0 : acc1) : (n == 0 ? acc2 : acc3);
#pragma unroll
            for (int i = 0; i < 16; ++i) {
                long oo = o0 + m * 32 + (i & 3) + 8 * (i >> 2) + 4 * lhi;
                if (oo < n_down)
                    out[oo * 64 + col] = fmaxf(A[i] * iv + bb, 0.f);
            }
        }
#undef IDXP
#undef GL1
#undef STAGE
#undef LDB
#undef COMPUTE
#undef REGION
}

extern "C" void kernel_launch(void* const* d_in, const int* in_sizes, int n_args,
                              void* d_out, int out_size, void* d_ws, size_t ws_size,
                              hipStream_t stream) {
    const float* feat    = (const float*)d_in[0];
    const float* w_down  = (const float*)d_in[1];
    const float* gamma_d = (const float*)d_in[2];
    const float* beta_d  = (const float*)d_in[3];
    const float* mean_d  = (const float*)d_in[4];
    const float* var_d   = (const float*)d_in[5];
    const float* w_ref   = (const float*)d_in[6];
    const float* gamma_r = (const float*)d_in[7];
    const float* beta_r  = (const float*)d_in[8];
    const float* mean_r  = (const float*)d_in[9];
    const float* var_r   = (const float*)d_in[10];
    const int*   gather_d  = (const int*)d_in[11];
    const int*   scatter_d = (const int*)d_in[12];
    const int*   gather_r  = (const int*)d_in[13];
    const int*   scatter_r = (const int*)d_in[14];

    int n_in   = in_sizes[0] / 32;
    int md     = in_sizes[11] / 16;
    int mr     = in_sizes[13] / 81;
    int n_down = out_size / 64;
    int nb64   = ((n_down + 63) / 64) * 64;      // permuted-table row stride (ints)

    // ws: ybf[(n_down+1)*64]bf16 | featbf[(n_in+1)*32]bf16 | wt[81*4096]bf16 |
    //     wtd[16*2048]bf16 | invP[84*nb64]i32 | invd[16*n_down]i32 (contig memset)
    char* ws = (char*)d_ws;
    size_t off = 0;
    auto alloc = [&](size_t bytes) { char* p = ws + off; off = (off + bytes + 255) & ~(size_t)255; return p; };
    unsigned short* ybf    = (unsigned short*)alloc((size_t)(n_down + 1) * 64 * 2);
    unsigned short* featbf = (unsigned short*)alloc((size_t)(n_in + 1) * 32 * 2);
    unsigned short* wt     = (unsigned short*)alloc((size_t)81 * 4096 * 2);
    unsigned short* wtd    = (unsigned short*)alloc((size_t)16 * 2048 * 2);
    int* invP = (int*)(ws + off);
    int* invd = invP + (size_t)84 * nb64;

    hipMemsetAsync(invP, 0xFF, ((size_t)84 * nb64 + (size_t)16 * n_down) * sizeof(int), stream);

    long td = 16L * md;
    build_inv<<<(int)((td + 255) / 256), 256, 0, stream>>>(gather_d, scatter_d, td, md, invd, n_down);
    long tr = 81L * mr;
    build_invP<<<(int)((tr + 255) / 256), 256, 0, stream>>>(gather_r, scatter_r, tr, mr, invP, n_down, nb64);

    long ft = ((long)n_in * 32 + 32) / 4;
    fcvt<<<(int)((ft + 255) / 256), 256, 0, stream>>>(feat, featbf, ybf + (size_t)n_down * 64, n_in);
    wcvt_r<<<81 * 4096 / 256, 256, 0, stream>>>(w_ref, wt);
    wcvt_d<<<16 * 2048 / 256, 256, 0, stream>>>(w_down, wtd);

    long wavesD  = ((long)n_down + 31) / 32;
    int  blocksD = (int)((wavesD * 64 + 255) / 256);
    conv_down_mfma<<<blocksD, 256, 0, stream>>>(featbf, wtd, invd,
                                                gamma_d, beta_d, mean_d, var_d,
                                                ybf, n_down, n_in);

    int blocksR = (n_down + 255) / 256;          // 4 waves x 64 rows per block
    conv_ref_mfma<<<blocksR, 256, 0, stream>>>(ybf, wt, invP,
                                               gamma_r, beta_r, mean_r, var_r,
                                               (float*)d_out, n_down, nb64, blocksR);
}